// Round 1
// baseline (991.852 us; speedup 1.0000x reference)
//
#include <hip/hip_runtime.h>

#define N_NODES 131072
#define N_EDGES 4194304
#define NUM_GRAPHS 128

// ---------------- degree histogram (edges only; self-loop added as +1 later) ----
__global__ __launch_bounds__(256) void k_deg(const int* __restrict__ dst,
                                             int* __restrict__ cnt) {
  int e = blockIdx.x * 256 + threadIdx.x;
  if (e < N_EDGES) atomicAdd(&cnt[dst[e]], 1);
}

// ---------------- per-node: dinv, CSR range reservation (wave-aggregated) -------
__global__ __launch_bounds__(256) void k_nodesetup(const int* __restrict__ cnt,
                                                   float* __restrict__ dinv,
                                                   int* __restrict__ node_off,
                                                   int* __restrict__ cursor,
                                                   int* __restrict__ counter) {
  int i = blockIdx.x * 256 + threadIdx.x;  // N_NODES % 256 == 0
  int c = cnt[i];
  dinv[i] = rsqrtf((float)(c + 1));  // deg includes self-loop -> >= 1
  int lane = threadIdx.x & 63;
  int incl = c;
  #pragma unroll
  for (int d = 1; d < 64; d <<= 1) {
    int v = __shfl_up(incl, d);
    if (lane >= d) incl += v;
  }
  int total = __shfl(incl, 63);
  int base = 0;
  if (lane == 63) base = atomicAdd(counter, total);
  base = __shfl(base, 63);
  int start = base + incl - c;  // exclusive scan within wave + global base
  node_off[i] = start;
  cursor[i] = start;
}

// ---------------- CSR fill: slot per edge via per-dst cursor ---------------------
__global__ __launch_bounds__(256) void k_fill(const int* __restrict__ src,
                                              const int* __restrict__ dst,
                                              const float* __restrict__ dinv,
                                              int* __restrict__ cursor,
                                              int2* __restrict__ csr) {
  int e = blockIdx.x * 256 + threadIdx.x;
  if (e >= N_EDGES) return;
  int s = src[e];
  int d = dst[e];
  int pos = atomicAdd(&cursor[d], 1);
  csr[pos] = make_int2(s, __float_as_int(dinv[s]));
}

// ---------------- h1_pre = x @ W1  (N x 3 . 3 x 16) ----------------------------
__global__ __launch_bounds__(256) void k_mm1(const float* __restrict__ x,
                                             const float* __restrict__ W1,
                                             float* __restrict__ h1p) {
  __shared__ float w[48];
  if (threadIdx.x < 48) w[threadIdx.x] = W1[threadIdx.x];
  __syncthreads();
  int i = blockIdx.x * 256 + threadIdx.x;
  float x0 = x[i * 3 + 0], x1 = x[i * 3 + 1], x2 = x[i * 3 + 2];
  float o[16];
  #pragma unroll
  for (int c = 0; c < 16; ++c)
    o[c] = x0 * w[c] + x1 * w[16 + c] + x2 * w[32 + c];
  float4* d4 = (float4*)(h1p + i * 16);
  d4[0] = make_float4(o[0], o[1], o[2], o[3]);
  d4[1] = make_float4(o[4], o[5], o[6], o[7]);
  d4[2] = make_float4(o[8], o[9], o[10], o[11]);
  d4[3] = make_float4(o[12], o[13], o[14], o[15]);
}

// ---------------- GCN aggregation (gather over CSR), +bias, ReLU ----------------
// out[i][c] = relu( dinv[i] * ( sum_e dinv[src_e]*hpre[src_e][c] + dinv[i]*hpre[i][c] ) + b[c] )
template <int F>
__global__ __launch_bounds__(256) void k_conv(const float* __restrict__ hpre,
                                              const int2* __restrict__ csr,
                                              const int* __restrict__ node_off,
                                              const int* __restrict__ cnt,
                                              const float* __restrict__ dinv,
                                              const float* __restrict__ bias,
                                              float* __restrict__ hout) {
  const int LOGF = (F == 16) ? 4 : 6;
  int t = blockIdx.x * 256 + threadIdx.x;
  int i = t >> LOGF;
  int c = t & (F - 1);
  int s0 = node_off[i];
  int n = cnt[i];
  float acc = 0.f;
  for (int k = 0; k < n; ++k) {
    int2 ew = csr[s0 + k];
    acc += __int_as_float(ew.y) * hpre[ew.x * F + c];
  }
  float di = dinv[i];
  acc += di * hpre[i * F + c];  // self-loop
  float v = di * acc + bias[c];
  hout[i * F + c] = fmaxf(v, 0.f);
}

// ---------------- h2_pre = h1 @ W2  (N x 16 . 16 x 64) -------------------------
__global__ __launch_bounds__(256) void k_mm2(const float* __restrict__ h1,
                                             const float* __restrict__ W2,
                                             float* __restrict__ h2p) {
  __shared__ float w[1024];
  for (int k = threadIdx.x; k < 1024; k += 256) w[k] = W2[k];
  __syncthreads();
  int t = blockIdx.x * 256 + threadIdx.x;
  int i = t >> 4;
  int g = (t & 15) * 4;
  float a0 = 0.f, a1 = 0.f, a2 = 0.f, a3 = 0.f;
  #pragma unroll
  for (int k = 0; k < 16; ++k) {
    float hv = h1[i * 16 + k];
    const float* wr = &w[k * 64 + g];
    a0 += hv * wr[0];
    a1 += hv * wr[1];
    a2 += hv * wr[2];
    a3 += hv * wr[3];
  }
  *(float4*)(h2p + i * 64 + g) = make_float4(a0, a1, a2, a3);
}

// ---------------- per-graph mean pool + MLP (no relu in FC layers) --------------
__global__ __launch_bounds__(1024) void k_poolfc(const float* __restrict__ h2,
                                                 const int* __restrict__ batch,
                                                 const float* __restrict__ fcw1,
                                                 const float* __restrict__ fcb1,
                                                 const float* __restrict__ fcw2,
                                                 const float* __restrict__ fcb2,
                                                 float* __restrict__ out) {
  int g = blockIdx.x;
  // lower_bound(g) and lower_bound(g+1) in sorted batch
  int lo = 0, hi = N_NODES;
  while (lo < hi) { int m = (lo + hi) >> 1; if (batch[m] < g) lo = m + 1; else hi = m; }
  int start = lo;
  lo = start; hi = N_NODES;
  while (lo < hi) { int m = (lo + hi) >> 1; if (batch[m] < g + 1) lo = m + 1; else hi = m; }
  int end = lo;
  int nn = end - start;

  int c = threadIdx.x & 63;
  int wv = threadIdx.x >> 6;  // 16 waves
  float acc = 0.f;
  for (int i = start + wv; i < end; i += 16) acc += h2[i * 64 + c];

  __shared__ float red[16 * 64];
  red[wv * 64 + c] = acc;
  __syncthreads();

  __shared__ float gmean[64];
  if (threadIdx.x < 64) {
    float s = 0.f;
    #pragma unroll
    for (int w = 0; w < 16; ++w) s += red[w * 64 + threadIdx.x];
    gmean[threadIdx.x] = s / fmaxf((float)nn, 1.0f);
  }
  __syncthreads();

  __shared__ float hid[32];
  if (threadIdx.x < 32) {
    float a = fcb1[threadIdx.x];
    #pragma unroll
    for (int k = 0; k < 64; ++k) a += gmean[k] * fcw1[k * 32 + threadIdx.x];
    hid[threadIdx.x] = a;
  }
  __syncthreads();

  if (threadIdx.x < 2) {
    float a = fcb2[threadIdx.x];
    #pragma unroll
    for (int k = 0; k < 32; ++k) a += hid[k] * fcw2[k * 2 + threadIdx.x];
    out[g * 2 + threadIdx.x] = a;
  }
}

extern "C" void kernel_launch(void* const* d_in, const int* in_sizes, int n_in,
                              void* d_out, int out_size, void* d_ws, size_t ws_size,
                              hipStream_t stream) {
  const float* x    = (const float*)d_in[0];
  const int*   ei   = (const int*)d_in[1];
  const int*   batch= (const int*)d_in[2];
  const float* W1   = (const float*)d_in[3];
  const float* b1   = (const float*)d_in[4];
  const float* W2   = (const float*)d_in[5];
  const float* b2   = (const float*)d_in[6];
  const float* fcw1 = (const float*)d_in[7];
  const float* fcb1 = (const float*)d_in[8];
  const float* fcw2 = (const float*)d_in[9];
  const float* fcb2 = (const float*)d_in[10];
  float* out = (float*)d_out;

  char* w = (char*)d_ws;
  size_t off = 0;
  auto alloc = [&](size_t bytes) {
    void* p = w + off;
    off += (bytes + 15) & ~(size_t)15;
    return p;
  };
  int*   cnt      = (int*)  alloc((size_t)N_NODES * 4);
  float* dinv     = (float*)alloc((size_t)N_NODES * 4);
  int*   node_off = (int*)  alloc((size_t)N_NODES * 4);
  int*   cursor   = (int*)  alloc((size_t)N_NODES * 4);
  int*   counter  = (int*)  alloc(16);
  int2*  csr      = (int2*) alloc((size_t)N_EDGES * 8);
  float* h1p      = (float*)alloc((size_t)N_NODES * 16 * 4);
  float* h1       = (float*)alloc((size_t)N_NODES * 16 * 4);
  float* h2p      = (float*)alloc((size_t)N_NODES * 64 * 4);
  float* h2       = (float*)alloc((size_t)N_NODES * 64 * 4);
  // total ~119.6 MB of d_ws

  const int* srcp = ei;
  const int* dstp = ei + N_EDGES;

  hipMemsetAsync(cnt, 0, (size_t)N_NODES * 4, stream);
  hipMemsetAsync(counter, 0, 16, stream);

  k_deg<<<N_EDGES / 256, 256, 0, stream>>>(dstp, cnt);
  k_nodesetup<<<N_NODES / 256, 256, 0, stream>>>(cnt, dinv, node_off, cursor, counter);
  k_fill<<<N_EDGES / 256, 256, 0, stream>>>(srcp, dstp, dinv, cursor, csr);
  k_mm1<<<N_NODES / 256, 256, 0, stream>>>(x, W1, h1p);
  k_conv<16><<<(N_NODES * 16) / 256, 256, 0, stream>>>(h1p, csr, node_off, cnt, dinv, b1, h1);
  k_mm2<<<(N_NODES * 16) / 256, 256, 0, stream>>>(h1, W2, h2p);
  k_conv<64><<<(N_NODES * 64) / 256, 256, 0, stream>>>(h2p, csr, node_off, cnt, dinv, b2, h2);
  k_poolfc<<<NUM_GRAPHS, 1024, 0, stream>>>(h2, batch, fcw1, fcb1, fcw2, fcb2, out);
}

// Round 2
// 761.640 us; speedup vs baseline: 1.3023x; 1.3023x over previous
//
#include <hip/hip_runtime.h>

#define N_NODES 131072
#define N_EDGES 4194304
#define NUM_GRAPHS 128

// ---------------- degree histogram (edges only; self-loop added as +1 later) ----
__global__ __launch_bounds__(256) void k_deg(const int* __restrict__ dst,
                                             int* __restrict__ cnt) {
  int e = blockIdx.x * 256 + threadIdx.x;
  if (e < N_EDGES) atomicAdd(&cnt[dst[e]], 1);
}

// ---- per-node: dinv, scaled x (xs = dinv*x, padded float4), CSR offsets --------
__global__ __launch_bounds__(256) void k_nodesetup(const int* __restrict__ cnt,
                                                   const float* __restrict__ x,
                                                   float* __restrict__ dinv,
                                                   float4* __restrict__ xs4,
                                                   int* __restrict__ node_off,
                                                   int* __restrict__ cursor,
                                                   int* __restrict__ counter) {
  int i = blockIdx.x * 256 + threadIdx.x;  // N_NODES % 256 == 0
  int c = cnt[i];
  float di = rsqrtf((float)(c + 1));  // deg includes self-loop -> >= 1
  dinv[i] = di;
  xs4[i] = make_float4(di * x[i * 3 + 0], di * x[i * 3 + 1], di * x[i * 3 + 2], 0.f);
  int lane = threadIdx.x & 63;
  int incl = c;
  #pragma unroll
  for (int d = 1; d < 64; d <<= 1) {
    int v = __shfl_up(incl, d);
    if (lane >= d) incl += v;
  }
  int total = __shfl(incl, 63);
  int base = 0;
  if (lane == 63) base = atomicAdd(counter, total);
  base = __shfl(base, 63);
  int start = base + incl - c;  // exclusive scan within wave + global base
  node_off[i] = start;
  cursor[i] = start;
}

// ---------------- CSR fill: slot per edge via per-dst cursor (4B entries) -------
__global__ __launch_bounds__(256) void k_fill(const int* __restrict__ src,
                                              const int* __restrict__ dst,
                                              int* __restrict__ cursor,
                                              int* __restrict__ csr) {
  int e = blockIdx.x * 256 + threadIdx.x;
  if (e >= N_EDGES) return;
  int s = src[e];
  int d = dst[e];
  int pos = atomicAdd(&cursor[d], 1);
  csr[pos] = s;
}

// ---------------- a3[i] = dinv_i * (sum_e xs[src_e] + xs[i])  (4 lanes/node) ----
__global__ __launch_bounds__(256) void k_agg3(const float* __restrict__ xs,
                                              const int* __restrict__ csr,
                                              const int* __restrict__ node_off,
                                              const int* __restrict__ cnt,
                                              const float* __restrict__ dinv,
                                              float* __restrict__ a3) {
  int t = blockIdx.x * 256 + threadIdx.x;
  int i = t >> 2;
  int c = t & 3;
  int s0 = node_off[i];
  int n = cnt[i];
  float acc = 0.f;
  for (int k = 0; k < n; ++k) {
    int s = csr[s0 + k];
    acc += xs[s * 4 + c];
  }
  acc += xs[i * 4 + c];  // self-loop (already dinv-scaled)
  a3[i * 4 + c] = dinv[i] * acc;
}

// ------- h1s[i][c] = dinv_i * relu(a3[i] @ W1 + b1)[c]   (16 lanes/node) --------
__global__ __launch_bounds__(256) void k_h1(const float* __restrict__ a3,
                                            const float* __restrict__ W1,
                                            const float* __restrict__ b1,
                                            const float* __restrict__ dinv,
                                            float* __restrict__ h1s) {
  __shared__ float w[48];
  __shared__ float b[16];
  if (threadIdx.x < 48) w[threadIdx.x] = W1[threadIdx.x];
  if (threadIdx.x < 16) b[threadIdx.x] = b1[threadIdx.x];
  __syncthreads();
  int t = blockIdx.x * 256 + threadIdx.x;
  int i = t >> 4;
  int c = t & 15;
  float a0 = a3[i * 4 + 0], a1 = a3[i * 4 + 1], a2 = a3[i * 4 + 2];
  float v = a0 * w[c] + a1 * w[16 + c] + a2 * w[32 + c] + b[c];
  h1s[i * 16 + c] = dinv[i] * fmaxf(v, 0.f);
}

// ------- agg1[i] = dinv_i * (sum_e h1s[src_e] + h1s[i])  (16 lanes/node) --------
__global__ __launch_bounds__(256) void k_agg16(const float* __restrict__ h1s,
                                               const int* __restrict__ csr,
                                               const int* __restrict__ node_off,
                                               const int* __restrict__ cnt,
                                               const float* __restrict__ dinv,
                                               float* __restrict__ agg1) {
  int t = blockIdx.x * 256 + threadIdx.x;
  int i = t >> 4;
  int c = t & 15;
  int s0 = node_off[i];
  int n = cnt[i];
  float acc = 0.f;
  for (int k = 0; k < n; ++k) {
    int s = csr[s0 + k];
    acc += h1s[s * 16 + c];
  }
  acc += h1s[i * 16 + c];  // self-loop
  agg1[i * 16 + c] = dinv[i] * acc;
}

// ---- per-graph: h2 = relu(agg1 @ W2 + b2) on the fly, mean-pool, FC MLP --------
__global__ __launch_bounds__(1024) void k_poolfc(const float* __restrict__ agg1,
                                                 const int* __restrict__ batch,
                                                 const float* __restrict__ W2,
                                                 const float* __restrict__ b2,
                                                 const float* __restrict__ fcw1,
                                                 const float* __restrict__ fcb1,
                                                 const float* __restrict__ fcw2,
                                                 const float* __restrict__ fcb2,
                                                 float* __restrict__ out) {
  __shared__ float w2s[1024];
  __shared__ float b2s[64];
  for (int k = threadIdx.x; k < 1024; k += 1024) w2s[k] = W2[k];
  if (threadIdx.x < 64) b2s[threadIdx.x] = b2[threadIdx.x];
  { // full 1024-entry load (the loop above only did one element per thread)
  }
  __syncthreads();

  int g = blockIdx.x;
  // lower_bound(g) and lower_bound(g+1) in sorted batch
  int lo = 0, hi = N_NODES;
  while (lo < hi) { int m = (lo + hi) >> 1; if (batch[m] < g) lo = m + 1; else hi = m; }
  int start = lo;
  lo = start; hi = N_NODES;
  while (lo < hi) { int m = (lo + hi) >> 1; if (batch[m] < g + 1) lo = m + 1; else hi = m; }
  int end = lo;
  int nn = end - start;

  int c = threadIdx.x & 63;
  int wv = threadIdx.x >> 6;  // 16 waves
  float acc = 0.f;
  for (int i = start + wv; i < end; i += 16) {
    const float* ar = agg1 + (size_t)i * 16;
    float v = b2s[c];
    #pragma unroll
    for (int k = 0; k < 16; ++k) v += ar[k] * w2s[k * 64 + c];  // ar[k] broadcasts
    acc += fmaxf(v, 0.f);
  }

  __shared__ float red[16 * 64];
  red[wv * 64 + c] = acc;
  __syncthreads();

  __shared__ float gmean[64];
  if (threadIdx.x < 64) {
    float s = 0.f;
    #pragma unroll
    for (int w = 0; w < 16; ++w) s += red[w * 64 + threadIdx.x];
    gmean[threadIdx.x] = s / fmaxf((float)nn, 1.0f);
  }
  __syncthreads();

  __shared__ float hid[32];
  if (threadIdx.x < 32) {
    float a = fcb1[threadIdx.x];
    #pragma unroll
    for (int k = 0; k < 64; ++k) a += gmean[k] * fcw1[k * 32 + threadIdx.x];
    hid[threadIdx.x] = a;
  }
  __syncthreads();

  if (threadIdx.x < 2) {
    float a = fcb2[threadIdx.x];
    #pragma unroll
    for (int k = 0; k < 32; ++k) a += hid[k] * fcw2[k * 2 + threadIdx.x];
    out[g * 2 + threadIdx.x] = a;
  }
}

extern "C" void kernel_launch(void* const* d_in, const int* in_sizes, int n_in,
                              void* d_out, int out_size, void* d_ws, size_t ws_size,
                              hipStream_t stream) {
  const float* x    = (const float*)d_in[0];
  const int*   ei   = (const int*)d_in[1];
  const int*   batch= (const int*)d_in[2];
  const float* W1   = (const float*)d_in[3];
  const float* b1   = (const float*)d_in[4];
  const float* W2   = (const float*)d_in[5];
  const float* b2   = (const float*)d_in[6];
  const float* fcw1 = (const float*)d_in[7];
  const float* fcb1 = (const float*)d_in[8];
  const float* fcw2 = (const float*)d_in[9];
  const float* fcb2 = (const float*)d_in[10];
  float* out = (float*)d_out;

  char* w = (char*)d_ws;
  size_t off = 0;
  auto alloc = [&](size_t bytes) {
    void* p = w + off;
    off += (bytes + 255) & ~(size_t)255;
    return p;
  };
  int*    cnt      = (int*)   alloc((size_t)N_NODES * 4);
  float*  dinv     = (float*) alloc((size_t)N_NODES * 4);
  int*    node_off = (int*)   alloc((size_t)N_NODES * 4);
  int*    cursor   = (int*)   alloc((size_t)N_NODES * 4);
  int*    counter  = (int*)   alloc(256);
  int*    csr      = (int*)   alloc((size_t)N_EDGES * 4);   // 16 MB
  float4* xs4      = (float4*)alloc((size_t)N_NODES * 16);  // 2 MB
  float*  a3       = (float*) alloc((size_t)N_NODES * 16);  // 2 MB
  float*  h1s      = (float*) alloc((size_t)N_NODES * 64);  // 8 MB
  float*  agg1     = (float*) alloc((size_t)N_NODES * 64);  // 8 MB

  const int* srcp = ei;
  const int* dstp = ei + N_EDGES;

  hipMemsetAsync(cnt, 0, (size_t)N_NODES * 4, stream);
  hipMemsetAsync(counter, 0, 256, stream);

  k_deg<<<N_EDGES / 256, 256, 0, stream>>>(dstp, cnt);
  k_nodesetup<<<N_NODES / 256, 256, 0, stream>>>(cnt, x, dinv, xs4, node_off, cursor, counter);
  k_fill<<<N_EDGES / 256, 256, 0, stream>>>(srcp, dstp, cursor, csr);
  k_agg3<<<(N_NODES * 4) / 256, 256, 0, stream>>>((const float*)xs4, csr, node_off, cnt, dinv, a3);
  k_h1<<<(N_NODES * 16) / 256, 256, 0, stream>>>(a3, W1, b1, dinv, h1s);
  k_agg16<<<(N_NODES * 16) / 256, 256, 0, stream>>>(h1s, csr, node_off, cnt, dinv, agg1);
  k_poolfc<<<NUM_GRAPHS, 1024, 0, stream>>>(agg1, batch, W2, b2, fcw1, fcb1, fcw2, fcb2, out);
}

// Round 3
// 525.683 us; speedup vs baseline: 1.8868x; 1.4489x over previous
//
#include <hip/hip_runtime.h>

#define N_NODES 131072
#define N_EDGES 4194304
#define NUM_GRAPHS 128

#define NB 512        // buckets
#define NPB 256       // nodes per bucket (N_NODES / NB)
#define BSHIFT 8      // dst>>8 = bucket, dst&255 = local node
#define BCAP 10240    // slots per bucket (mean 8192, sd ~90 -> +22 sigma)

// ---------------- init per-bucket cursors -------------------------------------
__global__ __launch_bounds__(512) void k_init(int* __restrict__ bcursor) {
  bcursor[threadIdx.x] = threadIdx.x * BCAP;
}

// ------- bin edges by dst bucket; batch-reserved contiguous runs ---------------
__global__ __launch_bounds__(1024) void k_binfill(const int* __restrict__ src,
                                                  const int* __restrict__ dst,
                                                  int* __restrict__ bcursor,
                                                  unsigned* __restrict__ binned) {
  __shared__ int hist[NB], base_[NB], rank_[NB];
  for (int k = threadIdx.x; k < NB; k += 1024) { hist[k] = 0; rank_[k] = 0; }
  __syncthreads();
  unsigned pk[16];
  int bk[16];
  int eb = blockIdx.x * 16384 + threadIdx.x;
  #pragma unroll
  for (int i = 0; i < 16; ++i) {
    int e = eb + i * 1024;
    int s = src[e], d = dst[e];
    bk[i] = d >> BSHIFT;
    pk[i] = ((unsigned)s << BSHIFT) | (unsigned)(d & (NPB - 1));
    atomicAdd(&hist[bk[i]], 1);
  }
  __syncthreads();
  for (int k = threadIdx.x; k < NB; k += 1024)
    base_[k] = atomicAdd(&bcursor[k], hist[k]);
  __syncthreads();
  #pragma unroll
  for (int i = 0; i < 16; ++i) {
    int r = atomicAdd(&rank_[bk[i]], 1);
    binned[base_[bk[i]] + r] = pk[i];
  }
}

// ------- per-bucket degree histogram -> dinv, xs = dinv * x (padded float4) ----
__global__ __launch_bounds__(256) void k_degB(const unsigned* __restrict__ binned,
                                              const int* __restrict__ bcursor,
                                              const float* __restrict__ x,
                                              float* __restrict__ dinv,
                                              float4* __restrict__ xs4) {
  __shared__ int dcount[NPB];
  dcount[threadIdx.x] = 0;
  __syncthreads();
  int b = blockIdx.x;
  int s0 = b * BCAP;
  int n = bcursor[b] - s0;
  for (int e = threadIdx.x; e < n; e += 256)
    atomicAdd(&dcount[binned[s0 + e] & (NPB - 1)], 1);
  __syncthreads();
  int node = b * NPB + threadIdx.x;
  float di = rsqrtf((float)(dcount[threadIdx.x] + 1));  // +1: self-loop
  dinv[node] = di;
  xs4[node] = make_float4(di * x[node * 3 + 0], di * x[node * 3 + 1],
                          di * x[node * 3 + 2], 0.f);
}

// ------- fused: scatter-aggregate xs (3 feats) + W1 projection + relu ----------
// h1s[i][c] = dinv_i * relu( (dinv_i*(sum_e xs[src] + xs[i])) @ W1 + b1 )[c]
__global__ __launch_bounds__(1024) void k_aggB3h1(const unsigned* __restrict__ binned,
                                                  const int* __restrict__ bcursor,
                                                  const float* __restrict__ xs,
                                                  const float4* __restrict__ xs4,
                                                  const float* __restrict__ dinv,
                                                  const float* __restrict__ W1,
                                                  const float* __restrict__ b1,
                                                  float* __restrict__ h1s) {
  __shared__ float acc[NPB * 4];
  __shared__ float w[48];
  __shared__ float bb[16];
  if (threadIdx.x < 48) w[threadIdx.x] = W1[threadIdx.x];
  if (threadIdx.x >= 64 && threadIdx.x < 80) bb[threadIdx.x - 64] = b1[threadIdx.x - 64];
  acc[threadIdx.x] = 0.f;
  __syncthreads();

  int b = blockIdx.x;
  int s0 = b * BCAP;
  int n = bcursor[b] - s0;
  int c = threadIdx.x & 3;
  int slot = threadIdx.x >> 2;  // 256 edges in flight
  #pragma unroll 2
  for (int e = slot; e < n; e += 256) {
    unsigned ent = binned[s0 + e];          // 4 lanes same addr -> broadcast
    int srcn = (int)(ent >> BSHIFT);
    int dl = (int)(ent & (NPB - 1));
    atomicAdd(&acc[dl * 4 + c], xs[srcn * 4 + c]);
  }
  __syncthreads();

  // epilogue: 1024 threads = 256 nodes x 4 lanes; lane q computes feats 4q..4q+3
  int dl = threadIdx.x >> 2;
  int q = threadIdx.x & 3;
  int node = b * NPB + dl;
  float di = dinv[node];
  float4 xself = xs4[node];
  float a0 = di * (acc[dl * 4 + 0] + xself.x);
  float a1 = di * (acc[dl * 4 + 1] + xself.y);
  float a2 = di * (acc[dl * 4 + 2] + xself.z);
  float o[4];
  #pragma unroll
  for (int j = 0; j < 4; ++j) {
    int cc = q * 4 + j;
    float v = a0 * w[cc] + a1 * w[16 + cc] + a2 * w[32 + cc] + bb[cc];
    o[j] = di * fmaxf(v, 0.f);
  }
  *(float4*)(h1s + (size_t)node * 16 + q * 4) = make_float4(o[0], o[1], o[2], o[3]);
}

// ------- scatter-aggregate h1s (16 feats): agg1 = dinv_i*(sum + self) ----------
__global__ __launch_bounds__(1024) void k_aggB16(const unsigned* __restrict__ binned,
                                                 const int* __restrict__ bcursor,
                                                 const float* __restrict__ h1s,
                                                 const float* __restrict__ dinv,
                                                 float* __restrict__ agg1) {
  __shared__ float acc[NPB * 16];  // 16 KB
  #pragma unroll
  for (int j = 0; j < 4; ++j) acc[j * 1024 + threadIdx.x] = 0.f;
  __syncthreads();

  int b = blockIdx.x;
  int s0 = b * BCAP;
  int n = bcursor[b] - s0;
  int c = threadIdx.x & 15;
  int slot = threadIdx.x >> 4;  // 64 edges in flight
  #pragma unroll 2
  for (int e = slot; e < n; e += 64) {
    unsigned ent = binned[s0 + e];          // 16 lanes same addr -> broadcast
    int srcn = (int)(ent >> BSHIFT);
    int dl = (int)(ent & (NPB - 1));
    atomicAdd(&acc[dl * 16 + c], h1s[srcn * 16 + c]);
  }
  __syncthreads();

  #pragma unroll
  for (int j = 0; j < 4; ++j) {
    int idx = j * 1024 + threadIdx.x;
    int dl = idx >> 4;
    int cc = idx & 15;
    int node = b * NPB + dl;
    agg1[(size_t)b * 4096 + idx] = dinv[node] * (acc[idx] + h1s[node * 16 + cc]);
  }
}

// ---- per-graph: h2 = relu(agg1 @ W2 + b2) on the fly, mean-pool, FC MLP --------
__global__ __launch_bounds__(1024) void k_poolfc(const float* __restrict__ agg1,
                                                 const int* __restrict__ batch,
                                                 const float* __restrict__ W2,
                                                 const float* __restrict__ b2,
                                                 const float* __restrict__ fcw1,
                                                 const float* __restrict__ fcb1,
                                                 const float* __restrict__ fcw2,
                                                 const float* __restrict__ fcb2,
                                                 float* __restrict__ out) {
  __shared__ float w2s[1024];
  __shared__ float b2s[64];
  w2s[threadIdx.x] = W2[threadIdx.x];
  if (threadIdx.x < 64) b2s[threadIdx.x] = b2[threadIdx.x];
  __syncthreads();

  int g = blockIdx.x;
  int lo = 0, hi = N_NODES;
  while (lo < hi) { int m = (lo + hi) >> 1; if (batch[m] < g) lo = m + 1; else hi = m; }
  int start = lo;
  lo = start; hi = N_NODES;
  while (lo < hi) { int m = (lo + hi) >> 1; if (batch[m] < g + 1) lo = m + 1; else hi = m; }
  int end = lo;
  int nn = end - start;

  int c = threadIdx.x & 63;
  int wv = threadIdx.x >> 6;  // 16 waves
  float acc = 0.f;
  for (int i = start + wv; i < end; i += 16) {
    const float* ar = agg1 + (size_t)i * 16;
    float v = b2s[c];
    #pragma unroll
    for (int k = 0; k < 16; ++k) v += ar[k] * w2s[k * 64 + c];
    acc += fmaxf(v, 0.f);
  }

  __shared__ float red[16 * 64];
  red[wv * 64 + c] = acc;
  __syncthreads();

  __shared__ float gmean[64];
  if (threadIdx.x < 64) {
    float s = 0.f;
    #pragma unroll
    for (int w = 0; w < 16; ++w) s += red[w * 64 + threadIdx.x];
    gmean[threadIdx.x] = s / fmaxf((float)nn, 1.0f);
  }
  __syncthreads();

  __shared__ float hid[32];
  if (threadIdx.x < 32) {
    float a = fcb1[threadIdx.x];
    #pragma unroll
    for (int k = 0; k < 64; ++k) a += gmean[k] * fcw1[k * 32 + threadIdx.x];
    hid[threadIdx.x] = a;
  }
  __syncthreads();

  if (threadIdx.x < 2) {
    float a = fcb2[threadIdx.x];
    #pragma unroll
    for (int k = 0; k < 32; ++k) a += hid[k] * fcw2[k * 2 + threadIdx.x];
    out[g * 2 + threadIdx.x] = a;
  }
}

extern "C" void kernel_launch(void* const* d_in, const int* in_sizes, int n_in,
                              void* d_out, int out_size, void* d_ws, size_t ws_size,
                              hipStream_t stream) {
  const float* x    = (const float*)d_in[0];
  const int*   ei   = (const int*)d_in[1];
  const int*   batch= (const int*)d_in[2];
  const float* W1   = (const float*)d_in[3];
  const float* b1   = (const float*)d_in[4];
  const float* W2   = (const float*)d_in[5];
  const float* b2   = (const float*)d_in[6];
  const float* fcw1 = (const float*)d_in[7];
  const float* fcb1 = (const float*)d_in[8];
  const float* fcw2 = (const float*)d_in[9];
  const float* fcb2 = (const float*)d_in[10];
  float* out = (float*)d_out;

  char* w = (char*)d_ws;
  size_t off = 0;
  auto alloc = [&](size_t bytes) {
    void* p = w + off;
    off += (bytes + 255) & ~(size_t)255;
    return p;
  };
  int*      bcursor = (int*)     alloc((size_t)NB * 4);
  unsigned* binned  = (unsigned*)alloc((size_t)NB * BCAP * 4);  // 21 MB
  float*    dinv    = (float*)   alloc((size_t)N_NODES * 4);
  float4*   xs4     = (float4*)  alloc((size_t)N_NODES * 16);   // 2 MB
  float*    h1s     = (float*)   alloc((size_t)N_NODES * 64);   // 8 MB
  float*    agg1    = (float*)   alloc((size_t)N_NODES * 64);   // 8 MB

  const int* srcp = ei;
  const int* dstp = ei + N_EDGES;

  k_init<<<1, 512, 0, stream>>>(bcursor);
  k_binfill<<<N_EDGES / 16384, 1024, 0, stream>>>(srcp, dstp, bcursor, binned);
  k_degB<<<NB, 256, 0, stream>>>(binned, bcursor, x, dinv, xs4);
  k_aggB3h1<<<NB, 1024, 0, stream>>>(binned, bcursor, (const float*)xs4, xs4, dinv, W1, b1, h1s);
  k_aggB16<<<NB, 1024, 0, stream>>>(binned, bcursor, h1s, dinv, agg1);
  k_poolfc<<<NUM_GRAPHS, 1024, 0, stream>>>(agg1, batch, W2, b2, fcw1, fcb1, fcw2, fcb2, out);
}

// Round 4
// 523.491 us; speedup vs baseline: 1.8947x; 1.0042x over previous
//
#include <hip/hip_runtime.h>
#include <hip/hip_fp16.h>

#define N_NODES 131072
#define N_EDGES 4194304
#define NUM_GRAPHS 128

#define NB 512        // buckets
#define NPB 256       // nodes per bucket (N_NODES / NB)
#define BSHIFT 8      // dst>>8 = bucket, dst&255 = local node
#define BCAP 10240    // slots per bucket (mean 8192, sd ~90 -> +22 sigma)

// ---------------- init per-bucket cursors -------------------------------------
__global__ __launch_bounds__(512) void k_init(int* __restrict__ bcursor) {
  bcursor[threadIdx.x] = threadIdx.x * BCAP;
}

// ------- bin edges by dst bucket; batch-reserved contiguous runs ---------------
__global__ __launch_bounds__(1024) void k_binfill(const int* __restrict__ src,
                                                  const int* __restrict__ dst,
                                                  int* __restrict__ bcursor,
                                                  unsigned* __restrict__ binned) {
  __shared__ int hist[NB], base_[NB], rank_[NB];
  for (int k = threadIdx.x; k < NB; k += 1024) { hist[k] = 0; rank_[k] = 0; }
  __syncthreads();
  unsigned pk[16];
  int bk[16];
  int eb = blockIdx.x * 16384 + threadIdx.x;
  #pragma unroll
  for (int i = 0; i < 16; ++i) {
    int e = eb + i * 1024;
    int s = src[e], d = dst[e];
    bk[i] = d >> BSHIFT;
    pk[i] = ((unsigned)s << BSHIFT) | (unsigned)(d & (NPB - 1));
    atomicAdd(&hist[bk[i]], 1);
  }
  __syncthreads();
  for (int k = threadIdx.x; k < NB; k += 1024)
    base_[k] = atomicAdd(&bcursor[k], hist[k]);
  __syncthreads();
  #pragma unroll
  for (int i = 0; i < 16; ++i) {
    int r = atomicAdd(&rank_[bk[i]], 1);
    binned[base_[bk[i]] + r] = pk[i];
  }
}

// ------- per-bucket degree histogram -> dinv, xs = dinv * x (padded float4) ----
__global__ __launch_bounds__(256) void k_degB(const unsigned* __restrict__ binned,
                                              const int* __restrict__ bcursor,
                                              const float* __restrict__ x,
                                              float* __restrict__ dinv,
                                              float4* __restrict__ xs4) {
  __shared__ int dcount[NPB];
  dcount[threadIdx.x] = 0;
  __syncthreads();
  int b = blockIdx.x;
  int s0 = b * BCAP;
  int n = bcursor[b] - s0;
  for (int e = threadIdx.x; e < n; e += 256) {
    unsigned ent = __builtin_nontemporal_load(&binned[s0 + e]);
    atomicAdd(&dcount[ent & (NPB - 1)], 1);
  }
  __syncthreads();
  int node = b * NPB + threadIdx.x;
  float di = rsqrtf((float)(dcount[threadIdx.x] + 1));  // +1: self-loop
  dinv[node] = di;
  xs4[node] = make_float4(di * x[node * 3 + 0], di * x[node * 3 + 1],
                          di * x[node * 3 + 2], 0.f);
}

// ------- fused: scatter-aggregate xs (3 feats) + W1 projection + relu ----------
// h1h[i][c] = fp16( dinv_i * relu( (dinv_i*(sum_e xs[src] + xs[i])) @ W1 + b1 )[c] )
__global__ __launch_bounds__(1024) void k_aggB3h1(const unsigned* __restrict__ binned,
                                                  const int* __restrict__ bcursor,
                                                  const float* __restrict__ xs,
                                                  const float4* __restrict__ xs4,
                                                  const float* __restrict__ dinv,
                                                  const float* __restrict__ W1,
                                                  const float* __restrict__ b1,
                                                  unsigned* __restrict__ h1h) {
  __shared__ float acc[NPB * 4];
  __shared__ float w[48];
  __shared__ float bb[16];
  if (threadIdx.x < 48) w[threadIdx.x] = W1[threadIdx.x];
  if (threadIdx.x >= 64 && threadIdx.x < 80) bb[threadIdx.x - 64] = b1[threadIdx.x - 64];
  acc[threadIdx.x] = 0.f;
  __syncthreads();

  int b = blockIdx.x;
  int s0 = b * BCAP;
  int n = bcursor[b] - s0;
  int c = threadIdx.x & 3;
  int slot = threadIdx.x >> 2;  // 256 edges in flight
  #pragma unroll 2
  for (int e = slot; e < n; e += 256) {
    unsigned ent = __builtin_nontemporal_load(&binned[s0 + e]);
    int srcn = (int)(ent >> BSHIFT);
    int dl = (int)(ent & (NPB - 1));
    atomicAdd(&acc[dl * 4 + c], xs[srcn * 4 + c]);
  }
  __syncthreads();

  // epilogue: 1024 threads = 256 nodes x 4 lanes; lane q computes feats 4q..4q+3
  int dl = threadIdx.x >> 2;
  int q = threadIdx.x & 3;
  int node = b * NPB + dl;
  float di = dinv[node];
  float4 xself = xs4[node];
  float a0 = di * (acc[dl * 4 + 0] + xself.x);
  float a1 = di * (acc[dl * 4 + 1] + xself.y);
  float a2 = di * (acc[dl * 4 + 2] + xself.z);
  float o[4];
  #pragma unroll
  for (int j = 0; j < 4; ++j) {
    int cc = q * 4 + j;
    float v = a0 * w[cc] + a1 * w[16 + cc] + a2 * w[32 + cc] + bb[cc];
    o[j] = di * fmaxf(v, 0.f);
  }
  __half2 p0 = __floats2half2_rn(o[0], o[1]);
  __half2 p1 = __floats2half2_rn(o[2], o[3]);
  uint2 st;
  st.x = *reinterpret_cast<unsigned*>(&p0);
  st.y = *reinterpret_cast<unsigned*>(&p1);
  *(uint2*)(h1h + (size_t)node * 8 + q * 2) = st;
}

// ------- scatter-aggregate h1 (16 feats, fp16 rows): agg1 = dinv_i*(sum+self) --
__global__ __launch_bounds__(1024) void k_aggB16(const unsigned* __restrict__ binned,
                                                 const int* __restrict__ bcursor,
                                                 const unsigned* __restrict__ h1h,
                                                 const float* __restrict__ dinv,
                                                 float* __restrict__ agg1) {
  __shared__ float acc[16 * 257];  // transposed + padded: acc[c][dl]
  for (int idx = threadIdx.x; idx < 16 * 257; idx += 1024) acc[idx] = 0.f;
  __syncthreads();

  int b = blockIdx.x;
  int s0 = b * BCAP;
  int n = bcursor[b] - s0;
  int c2 = threadIdx.x & 7;     // feature-pair index
  int slot = threadIdx.x >> 3;  // 128 edges in flight
  #pragma unroll 2
  for (int e = slot; e < n; e += 128) {
    unsigned ent = __builtin_nontemporal_load(&binned[s0 + e]);
    int srcn = (int)(ent >> BSHIFT);
    int dl = (int)(ent & (NPB - 1));
    unsigned hv = h1h[srcn * 8 + c2];  // 8 lanes x 4B = one 32B row
    __half2 h2v = *reinterpret_cast<const __half2*>(&hv);
    atomicAdd(&acc[(2 * c2) * 257 + dl], __low2float(h2v));
    atomicAdd(&acc[(2 * c2 + 1) * 257 + dl], __high2float(h2v));
  }
  __syncthreads();

  // epilogue: 256 nodes x 4 lanes; lane q -> feats 4q..4q+3
  int dl = threadIdx.x >> 2;
  int q = threadIdx.x & 3;
  int node = b * NPB + dl;
  float di = dinv[node];
  unsigned sv0 = h1h[(size_t)node * 8 + 2 * q];
  unsigned sv1 = h1h[(size_t)node * 8 + 2 * q + 1];
  __half2 s0h = *reinterpret_cast<const __half2*>(&sv0);
  __half2 s1h = *reinterpret_cast<const __half2*>(&sv1);
  float o0 = di * (acc[(4 * q + 0) * 257 + dl] + __low2float(s0h));
  float o1 = di * (acc[(4 * q + 1) * 257 + dl] + __high2float(s0h));
  float o2 = di * (acc[(4 * q + 2) * 257 + dl] + __low2float(s1h));
  float o3 = di * (acc[(4 * q + 3) * 257 + dl] + __high2float(s1h));
  *(float4*)(agg1 + (size_t)node * 16 + q * 4) = make_float4(o0, o1, o2, o3);
}

// ---- per-graph: h2 = relu(agg1 @ W2 + b2) on the fly, mean-pool, FC MLP --------
__global__ __launch_bounds__(1024) void k_poolfc(const float* __restrict__ agg1,
                                                 const int* __restrict__ batch,
                                                 const float* __restrict__ W2,
                                                 const float* __restrict__ b2,
                                                 const float* __restrict__ fcw1,
                                                 const float* __restrict__ fcb1,
                                                 const float* __restrict__ fcw2,
                                                 const float* __restrict__ fcb2,
                                                 float* __restrict__ out) {
  __shared__ float w2s[1024];
  __shared__ float b2s[64];
  w2s[threadIdx.x] = W2[threadIdx.x];
  if (threadIdx.x < 64) b2s[threadIdx.x] = b2[threadIdx.x];
  __syncthreads();

  int g = blockIdx.x;
  int lo = 0, hi = N_NODES;
  while (lo < hi) { int m = (lo + hi) >> 1; if (batch[m] < g) lo = m + 1; else hi = m; }
  int start = lo;
  lo = start; hi = N_NODES;
  while (lo < hi) { int m = (lo + hi) >> 1; if (batch[m] < g + 1) lo = m + 1; else hi = m; }
  int end = lo;
  int nn = end - start;

  int c = threadIdx.x & 63;
  int wv = threadIdx.x >> 6;  // 16 waves
  float acc = 0.f;
  for (int i = start + wv; i < end; i += 16) {
    const float* ar = agg1 + (size_t)i * 16;
    float v = b2s[c];
    #pragma unroll
    for (int k = 0; k < 16; ++k) v += ar[k] * w2s[k * 64 + c];
    acc += fmaxf(v, 0.f);
  }

  __shared__ float red[16 * 64];
  red[wv * 64 + c] = acc;
  __syncthreads();

  __shared__ float gmean[64];
  if (threadIdx.x < 64) {
    float s = 0.f;
    #pragma unroll
    for (int w = 0; w < 16; ++w) s += red[w * 64 + threadIdx.x];
    gmean[threadIdx.x] = s / fmaxf((float)nn, 1.0f);
  }
  __syncthreads();

  __shared__ float hid[32];
  if (threadIdx.x < 32) {
    float a = fcb1[threadIdx.x];
    #pragma unroll
    for (int k = 0; k < 64; ++k) a += gmean[k] * fcw1[k * 32 + threadIdx.x];
    hid[threadIdx.x] = a;
  }
  __syncthreads();

  if (threadIdx.x < 2) {
    float a = fcb2[threadIdx.x];
    #pragma unroll
    for (int k = 0; k < 32; ++k) a += hid[k] * fcw2[k * 2 + threadIdx.x];
    out[g * 2 + threadIdx.x] = a;
  }
}

extern "C" void kernel_launch(void* const* d_in, const int* in_sizes, int n_in,
                              void* d_out, int out_size, void* d_ws, size_t ws_size,
                              hipStream_t stream) {
  const float* x    = (const float*)d_in[0];
  const int*   ei   = (const int*)d_in[1];
  const int*   batch= (const int*)d_in[2];
  const float* W1   = (const float*)d_in[3];
  const float* b1   = (const float*)d_in[4];
  const float* W2   = (const float*)d_in[5];
  const float* b2   = (const float*)d_in[6];
  const float* fcw1 = (const float*)d_in[7];
  const float* fcb1 = (const float*)d_in[8];
  const float* fcw2 = (const float*)d_in[9];
  const float* fcb2 = (const float*)d_in[10];
  float* out = (float*)d_out;

  char* w = (char*)d_ws;
  size_t off = 0;
  auto alloc = [&](size_t bytes) {
    void* p = w + off;
    off += (bytes + 255) & ~(size_t)255;
    return p;
  };
  int*      bcursor = (int*)     alloc((size_t)NB * 4);
  unsigned* binned  = (unsigned*)alloc((size_t)NB * BCAP * 4);  // 21 MB
  float*    dinv    = (float*)   alloc((size_t)N_NODES * 4);
  float4*   xs4     = (float4*)  alloc((size_t)N_NODES * 16);   // 2 MB
  unsigned* h1h     = (unsigned*)alloc((size_t)N_NODES * 32);   // 4 MB fp16
  float*    agg1    = (float*)   alloc((size_t)N_NODES * 64);   // 8 MB

  const int* srcp = ei;
  const int* dstp = ei + N_EDGES;

  k_init<<<1, 512, 0, stream>>>(bcursor);
  k_binfill<<<N_EDGES / 16384, 1024, 0, stream>>>(srcp, dstp, bcursor, binned);
  k_degB<<<NB, 256, 0, stream>>>(binned, bcursor, x, dinv, xs4);
  k_aggB3h1<<<NB, 1024, 0, stream>>>(binned, bcursor, (const float*)xs4, xs4, dinv, W1, b1, h1h);
  k_aggB16<<<NB, 1024, 0, stream>>>(binned, bcursor, h1h, dinv, agg1);
  k_poolfc<<<NUM_GRAPHS, 1024, 0, stream>>>(agg1, batch, W2, b2, fcw1, fcb1, fcw2, fcb2, out);
}

// Round 5
// 170.669 us; speedup vs baseline: 5.8115x; 3.0673x over previous
//
#include <hip/hip_runtime.h>
#include <hip/hip_fp16.h>

#define N_NODES 131072
#define N_EDGES 4194304
#define NUM_GRAPHS 128

#define NB 512        // buckets
#define NPB 256       // nodes per bucket (N_NODES / NB)
#define BSHIFT 8      // dst>>8 = bucket, dst&255 = local node
#define BCAP 10240    // slots per bucket (mean 8192, sd ~90 -> +22 sigma)

// ---------------- init per-bucket cursors -------------------------------------
__global__ __launch_bounds__(512) void k_init(int* __restrict__ bcursor) {
  bcursor[threadIdx.x] = threadIdx.x * BCAP;
}

// ------- bin edges by dst bucket; batch-reserved contiguous runs ---------------
__global__ __launch_bounds__(1024) void k_binfill(const int* __restrict__ src,
                                                  const int* __restrict__ dst,
                                                  int* __restrict__ bcursor,
                                                  unsigned* __restrict__ binned) {
  __shared__ int hist[NB], base_[NB], rank_[NB];
  for (int k = threadIdx.x; k < NB; k += 1024) { hist[k] = 0; rank_[k] = 0; }
  __syncthreads();
  unsigned pk[16];
  int bk[16];
  int eb = blockIdx.x * 16384 + threadIdx.x;
  #pragma unroll
  for (int i = 0; i < 16; ++i) {
    int e = eb + i * 1024;
    int s = src[e], d = dst[e];
    bk[i] = d >> BSHIFT;
    pk[i] = ((unsigned)s << BSHIFT) | (unsigned)(d & (NPB - 1));
    atomicAdd(&hist[bk[i]], 1);
  }
  __syncthreads();
  for (int k = threadIdx.x; k < NB; k += 1024)
    base_[k] = atomicAdd(&bcursor[k], hist[k]);
  __syncthreads();
  #pragma unroll
  for (int i = 0; i < 16; ++i) {
    int r = atomicAdd(&rank_[bk[i]], 1);
    binned[base_[bk[i]] + r] = pk[i];
  }
}

// ------- per-bucket counting sort -> CSR; also dinv, xs = dinv*x (padded) ------
__global__ __launch_bounds__(1024) void k_sortB(const unsigned* __restrict__ binned,
                                                const int* __restrict__ bcursor,
                                                const float* __restrict__ x,
                                                float* __restrict__ dinv,
                                                float4* __restrict__ xs4,
                                                int* __restrict__ node_off,
                                                int* __restrict__ cnt,
                                                int* __restrict__ csrg) {
  __shared__ int dcount[NPB];
  __shared__ int cursor[NPB];
  __shared__ int wsum[4];
  int tid = threadIdx.x;
  if (tid < NPB) dcount[tid] = 0;
  __syncthreads();
  int b = blockIdx.x;
  int s0 = b * BCAP;
  int n = bcursor[b] - s0;
  for (int e = tid; e < n; e += 1024)
    atomicAdd(&dcount[binned[s0 + e] & (NPB - 1)], 1);
  __syncthreads();
  int v = 0, incl = 0;
  if (tid < NPB) {
    v = dcount[tid];
    incl = v;
    #pragma unroll
    for (int d = 1; d < 64; d <<= 1) {
      int t = __shfl_up(incl, d);
      if ((tid & 63) >= d) incl += t;
    }
    if ((tid & 63) == 63) wsum[tid >> 6] = incl;
  }
  __syncthreads();
  if (tid < NPB) {
    int base = 0;
    int wv = tid >> 6;
    for (int w2 = 0; w2 < wv; ++w2) base += wsum[w2];
    int pref = base + incl - v;  // exclusive prefix within bucket
    cursor[tid] = pref;
    int node = b * NPB + tid;
    node_off[node] = pref;
    cnt[node] = v;
    float di = rsqrtf((float)(v + 1));  // +1: self-loop
    dinv[node] = di;
    xs4[node] = make_float4(di * x[node * 3 + 0], di * x[node * 3 + 1],
                            di * x[node * 3 + 2], 0.f);
  }
  __syncthreads();
  for (int e = tid; e < n; e += 1024) {
    unsigned ent = binned[s0 + e];
    int key = (int)(ent & (NPB - 1));
    int pos = atomicAdd(&cursor[key], 1);
    csrg[s0 + pos] = (int)(ent >> BSHIFT);  // random 4B write within 40KB region
  }
}

// ------- fused: CSR gather-agg of xs (3 feats) + W1 proj + relu -> fp16 --------
// h1h[i][c] = fp16( dinv_i * relu( (dinv_i*(sum_e xs[src] + xs[i])) @ W1 + b1 )[c] )
__global__ __launch_bounds__(1024) void k_agg3h1(const int* __restrict__ csrg,
                                                 const int* __restrict__ node_off,
                                                 const int* __restrict__ cnt,
                                                 const float* __restrict__ xs,
                                                 const float4* __restrict__ xs4,
                                                 const float* __restrict__ dinv,
                                                 const float* __restrict__ W1,
                                                 const float* __restrict__ b1,
                                                 unsigned* __restrict__ h1h) {
  __shared__ float w[48];
  __shared__ float bb[16];
  __shared__ float accS[NPB * 4];
  if (threadIdx.x < 48) w[threadIdx.x] = W1[threadIdx.x];
  if (threadIdx.x >= 64 && threadIdx.x < 80) bb[threadIdx.x - 64] = b1[threadIdx.x - 64];

  int b = blockIdx.x;
  int dl = threadIdx.x >> 2;
  int q = threadIdx.x & 3;
  int node = b * NPB + dl;
  int s0 = b * BCAP + node_off[node];
  int len = cnt[node];
  float acc = 0.f;
  #pragma unroll 4
  for (int k = 0; k < len; ++k) {
    int srcn = csrg[s0 + k];          // 4 lanes same addr -> broadcast
    acc += xs[srcn * 4 + q];          // lanes 0..3 read 16B contiguous (q=3: pad)
  }
  accS[threadIdx.x] = acc;
  __syncthreads();

  float di = dinv[node];
  float4 xself = xs4[node];
  float a0 = di * (accS[dl * 4 + 0] + xself.x);
  float a1 = di * (accS[dl * 4 + 1] + xself.y);
  float a2 = di * (accS[dl * 4 + 2] + xself.z);
  float o[4];
  #pragma unroll
  for (int j = 0; j < 4; ++j) {
    int cc = q * 4 + j;
    float vv = a0 * w[cc] + a1 * w[16 + cc] + a2 * w[32 + cc] + bb[cc];
    o[j] = di * fmaxf(vv, 0.f);
  }
  __half2 p0 = __floats2half2_rn(o[0], o[1]);
  __half2 p1 = __floats2half2_rn(o[2], o[3]);
  uint2 st;
  st.x = *reinterpret_cast<unsigned*>(&p0);
  st.y = *reinterpret_cast<unsigned*>(&p1);
  *(uint2*)(h1h + (size_t)node * 8 + q * 2) = st;
}

// ------- CSR gather-agg of h1 (16 feats fp16), register accumulation -----------
// agg1[i] = dinv_i * (sum_e h1[src] + h1[i])
__global__ __launch_bounds__(1024) void k_agg16(const int* __restrict__ csrg,
                                                const int* __restrict__ node_off,
                                                const int* __restrict__ cnt,
                                                const unsigned* __restrict__ h1h,
                                                const float* __restrict__ dinv,
                                                float* __restrict__ agg1) {
  int b = blockIdx.x;
  int dl = threadIdx.x >> 2;
  int q = threadIdx.x & 3;
  int node = b * NPB + dl;
  int s0 = b * BCAP + node_off[node];
  int len = cnt[node];
  float o0 = 0.f, o1 = 0.f, o2 = 0.f, o3 = 0.f;
  #pragma unroll 4
  for (int k = 0; k < len; ++k) {
    int srcn = csrg[s0 + k];                                   // broadcast
    uint2 hv = *(const uint2*)(h1h + (size_t)srcn * 8 + q * 2); // 4 lanes = 32B row
    __half2 p0 = *reinterpret_cast<const __half2*>(&hv.x);
    __half2 p1 = *reinterpret_cast<const __half2*>(&hv.y);
    o0 += __low2float(p0); o1 += __high2float(p0);
    o2 += __low2float(p1); o3 += __high2float(p1);
  }
  float di = dinv[node];
  uint2 sv = *(const uint2*)(h1h + (size_t)node * 8 + q * 2);
  __half2 s0h = *reinterpret_cast<const __half2*>(&sv.x);
  __half2 s1h = *reinterpret_cast<const __half2*>(&sv.y);
  o0 = di * (o0 + __low2float(s0h));
  o1 = di * (o1 + __high2float(s0h));
  o2 = di * (o2 + __low2float(s1h));
  o3 = di * (o3 + __high2float(s1h));
  *(float4*)(agg1 + (size_t)node * 16 + q * 4) = make_float4(o0, o1, o2, o3);
}

// ---- per-graph: h2 = relu(agg1 @ W2 + b2) on the fly, mean-pool, FC MLP --------
__global__ __launch_bounds__(1024) void k_poolfc(const float* __restrict__ agg1,
                                                 const int* __restrict__ batch,
                                                 const float* __restrict__ W2,
                                                 const float* __restrict__ b2,
                                                 const float* __restrict__ fcw1,
                                                 const float* __restrict__ fcb1,
                                                 const float* __restrict__ fcw2,
                                                 const float* __restrict__ fcb2,
                                                 float* __restrict__ out) {
  __shared__ float w2s[1024];
  __shared__ float b2s[64];
  w2s[threadIdx.x] = W2[threadIdx.x];
  if (threadIdx.x < 64) b2s[threadIdx.x] = b2[threadIdx.x];
  __syncthreads();

  int g = blockIdx.x;
  int lo = 0, hi = N_NODES;
  while (lo < hi) { int m = (lo + hi) >> 1; if (batch[m] < g) lo = m + 1; else hi = m; }
  int start = lo;
  lo = start; hi = N_NODES;
  while (lo < hi) { int m = (lo + hi) >> 1; if (batch[m] < g + 1) lo = m + 1; else hi = m; }
  int end = lo;
  int nn = end - start;

  int c = threadIdx.x & 63;
  int wv = threadIdx.x >> 6;  // 16 waves
  float acc = 0.f;
  for (int i = start + wv; i < end; i += 16) {
    const float* ar = agg1 + (size_t)i * 16;
    float v = b2s[c];
    #pragma unroll
    for (int k = 0; k < 16; ++k) v += ar[k] * w2s[k * 64 + c];
    acc += fmaxf(v, 0.f);
  }

  __shared__ float red[16 * 64];
  red[wv * 64 + c] = acc;
  __syncthreads();

  __shared__ float gmean[64];
  if (threadIdx.x < 64) {
    float s = 0.f;
    #pragma unroll
    for (int w = 0; w < 16; ++w) s += red[w * 64 + threadIdx.x];
    gmean[threadIdx.x] = s / fmaxf((float)nn, 1.0f);
  }
  __syncthreads();

  __shared__ float hid[32];
  if (threadIdx.x < 32) {
    float a = fcb1[threadIdx.x];
    #pragma unroll
    for (int k = 0; k < 64; ++k) a += gmean[k] * fcw1[k * 32 + threadIdx.x];
    hid[threadIdx.x] = a;
  }
  __syncthreads();

  if (threadIdx.x < 2) {
    float a = fcb2[threadIdx.x];
    #pragma unroll
    for (int k = 0; k < 32; ++k) a += hid[k] * fcw2[k * 2 + threadIdx.x];
    out[g * 2 + threadIdx.x] = a;
  }
}

extern "C" void kernel_launch(void* const* d_in, const int* in_sizes, int n_in,
                              void* d_out, int out_size, void* d_ws, size_t ws_size,
                              hipStream_t stream) {
  const float* x    = (const float*)d_in[0];
  const int*   ei   = (const int*)d_in[1];
  const int*   batch= (const int*)d_in[2];
  const float* W1   = (const float*)d_in[3];
  const float* b1   = (const float*)d_in[4];
  const float* W2   = (const float*)d_in[5];
  const float* b2   = (const float*)d_in[6];
  const float* fcw1 = (const float*)d_in[7];
  const float* fcb1 = (const float*)d_in[8];
  const float* fcw2 = (const float*)d_in[9];
  const float* fcb2 = (const float*)d_in[10];
  float* out = (float*)d_out;

  char* w = (char*)d_ws;
  size_t off = 0;
  auto alloc = [&](size_t bytes) {
    void* p = w + off;
    off += (bytes + 255) & ~(size_t)255;
    return p;
  };
  int*      bcursor  = (int*)     alloc((size_t)NB * 4);
  unsigned* binned   = (unsigned*)alloc((size_t)NB * BCAP * 4);  // 21 MB
  int*      csrg     = (int*)     alloc((size_t)NB * BCAP * 4);  // 21 MB
  float*    dinv     = (float*)   alloc((size_t)N_NODES * 4);
  float4*   xs4      = (float4*)  alloc((size_t)N_NODES * 16);   // 2 MB
  int*      node_off = (int*)     alloc((size_t)N_NODES * 4);
  int*      cnt      = (int*)     alloc((size_t)N_NODES * 4);
  unsigned* h1h      = (unsigned*)alloc((size_t)N_NODES * 32);   // 4 MB fp16
  float*    agg1     = (float*)   alloc((size_t)N_NODES * 64);   // 8 MB

  const int* srcp = ei;
  const int* dstp = ei + N_EDGES;

  k_init<<<1, 512, 0, stream>>>(bcursor);
  k_binfill<<<N_EDGES / 16384, 1024, 0, stream>>>(srcp, dstp, bcursor, binned);
  k_sortB<<<NB, 1024, 0, stream>>>(binned, bcursor, x, dinv, xs4, node_off, cnt, csrg);
  k_agg3h1<<<NB, 1024, 0, stream>>>(csrg, node_off, cnt, (const float*)xs4, xs4, dinv, W1, b1, h1h);
  k_agg16<<<NB, 1024, 0, stream>>>(csrg, node_off, cnt, h1h, dinv, agg1);
  k_poolfc<<<NUM_GRAPHS, 1024, 0, stream>>>(agg1, batch, W2, b2, fcw1, fcb1, fcw2, fcb2, out);
}

// Round 6
// 148.518 us; speedup vs baseline: 6.6783x; 1.1492x over previous
//
#include <hip/hip_runtime.h>
#include <hip/hip_fp16.h>

#define N_NODES 131072
#define N_EDGES 4194304
#define NUM_GRAPHS 128

#define NB 512        // buckets
#define NPB 256       // nodes per bucket (N_NODES / NB)
#define BSHIFT 8      // dst>>8 = bucket, dst&255 = local node
#define BCAP 10240    // slots per bucket (mean 8192, sd ~90 -> +22 sigma)
#define GSPAN 8       // max graphs tracked in LDS per bucket (fallback: global)

// ---------------- init per-bucket cursors -------------------------------------
__global__ __launch_bounds__(512) void k_init(int* __restrict__ bcursor) {
  bcursor[threadIdx.x] = threadIdx.x * BCAP;
}

// ------- bin edges by dst bucket; batch-reserved contiguous runs ---------------
__global__ __launch_bounds__(1024) void k_binfill(const int* __restrict__ src,
                                                  const int* __restrict__ dst,
                                                  int* __restrict__ bcursor,
                                                  unsigned* __restrict__ binned) {
  __shared__ int hist[NB], base_[NB], rank_[NB];
  for (int k = threadIdx.x; k < NB; k += 1024) { hist[k] = 0; rank_[k] = 0; }
  __syncthreads();
  unsigned pk[16];
  int bk[16];
  int eb = blockIdx.x * 16384 + threadIdx.x;
  #pragma unroll
  for (int i = 0; i < 16; ++i) {
    int e = eb + i * 1024;
    int s = src[e], d = dst[e];
    bk[i] = d >> BSHIFT;
    pk[i] = ((unsigned)s << BSHIFT) | (unsigned)(d & (NPB - 1));
    atomicAdd(&hist[bk[i]], 1);
  }
  __syncthreads();
  for (int k = threadIdx.x; k < NB; k += 1024)
    base_[k] = atomicAdd(&bcursor[k], hist[k]);
  __syncthreads();
  #pragma unroll
  for (int i = 0; i < 16; ++i) {
    int r = atomicAdd(&rank_[bk[i]], 1);
    binned[base_[bk[i]] + r] = pk[i];
  }
}

// ------- per-bucket counting sort -> CSR; also dinv, xs = dinv*x (padded) ------
__global__ __launch_bounds__(1024) void k_sortB(const unsigned* __restrict__ binned,
                                                const int* __restrict__ bcursor,
                                                const float* __restrict__ x,
                                                float* __restrict__ dinv,
                                                float4* __restrict__ xs4,
                                                int* __restrict__ node_off,
                                                int* __restrict__ cnt,
                                                int* __restrict__ csrg) {
  __shared__ int dcount[NPB];
  __shared__ int cursor[NPB];
  __shared__ int wsum[4];
  int tid = threadIdx.x;
  if (tid < NPB) dcount[tid] = 0;
  __syncthreads();
  int b = blockIdx.x;
  int s0 = b * BCAP;
  int n = bcursor[b] - s0;
  for (int e = tid; e < n; e += 1024)
    atomicAdd(&dcount[binned[s0 + e] & (NPB - 1)], 1);
  __syncthreads();
  int v = 0, incl = 0;
  if (tid < NPB) {
    v = dcount[tid];
    incl = v;
    #pragma unroll
    for (int d = 1; d < 64; d <<= 1) {
      int t = __shfl_up(incl, d);
      if ((tid & 63) >= d) incl += t;
    }
    if ((tid & 63) == 63) wsum[tid >> 6] = incl;
  }
  __syncthreads();
  if (tid < NPB) {
    int base = 0;
    int wv = tid >> 6;
    for (int w2 = 0; w2 < wv; ++w2) base += wsum[w2];
    int pref = base + incl - v;  // exclusive prefix within bucket
    cursor[tid] = pref;
    int node = b * NPB + tid;
    node_off[node] = pref;
    cnt[node] = v;
    float di = rsqrtf((float)(v + 1));  // +1: self-loop
    dinv[node] = di;
    xs4[node] = make_float4(di * x[node * 3 + 0], di * x[node * 3 + 1],
                            di * x[node * 3 + 2], 0.f);
  }
  __syncthreads();
  for (int e = tid; e < n; e += 1024) {
    unsigned ent = binned[s0 + e];
    int key = (int)(ent & (NPB - 1));
    int pos = atomicAdd(&cursor[key], 1);
    csrg[s0 + pos] = (int)(ent >> BSHIFT);  // random 4B write within 40KB region
  }
}

// ------- fused: CSR gather-agg of xs (3 feats) + W1 proj + relu -> fp16 --------
__global__ __launch_bounds__(1024) void k_agg3h1(const int* __restrict__ csrg,
                                                 const int* __restrict__ node_off,
                                                 const int* __restrict__ cnt,
                                                 const float* __restrict__ xs,
                                                 const float4* __restrict__ xs4,
                                                 const float* __restrict__ dinv,
                                                 const float* __restrict__ W1,
                                                 const float* __restrict__ b1,
                                                 unsigned* __restrict__ h1h) {
  __shared__ float w[48];
  __shared__ float bb[16];
  __shared__ float accS[NPB * 4];
  if (threadIdx.x < 48) w[threadIdx.x] = W1[threadIdx.x];
  if (threadIdx.x >= 64 && threadIdx.x < 80) bb[threadIdx.x - 64] = b1[threadIdx.x - 64];

  int b = blockIdx.x;
  int dl = threadIdx.x >> 2;
  int q = threadIdx.x & 3;
  int node = b * NPB + dl;
  int s0 = b * BCAP + node_off[node];
  int len = cnt[node];
  float acc = 0.f;
  #pragma unroll 4
  for (int k = 0; k < len; ++k) {
    int srcn = csrg[s0 + k];          // 4 lanes same addr -> broadcast
    acc += xs[srcn * 4 + q];          // lanes 0..3 read 16B contiguous
  }
  accS[threadIdx.x] = acc;
  __syncthreads();

  float di = dinv[node];
  float4 xself = xs4[node];
  float a0 = di * (accS[dl * 4 + 0] + xself.x);
  float a1 = di * (accS[dl * 4 + 1] + xself.y);
  float a2 = di * (accS[dl * 4 + 2] + xself.z);
  float o[4];
  #pragma unroll
  for (int j = 0; j < 4; ++j) {
    int cc = q * 4 + j;
    float vv = a0 * w[cc] + a1 * w[16 + cc] + a2 * w[32 + cc] + bb[cc];
    o[j] = di * fmaxf(vv, 0.f);
  }
  __half2 p0 = __floats2half2_rn(o[0], o[1]);
  __half2 p1 = __floats2half2_rn(o[2], o[3]);
  uint2 st;
  st.x = *reinterpret_cast<unsigned*>(&p0);
  st.y = *reinterpret_cast<unsigned*>(&p1);
  *(uint2*)(h1h + (size_t)node * 8 + q * 2) = st;
}

// ------- CSR gather-agg of h1 + fused h2 = relu(agg@W2+b2) + per-graph pool ----
__global__ __launch_bounds__(1024) void k_agg16pool(const int* __restrict__ csrg,
                                                    const int* __restrict__ node_off,
                                                    const int* __restrict__ cnt,
                                                    const unsigned* __restrict__ h1h,
                                                    const float* __restrict__ dinv,
                                                    const int* __restrict__ batch,
                                                    const float* __restrict__ W2,
                                                    const float* __restrict__ b2,
                                                    float* __restrict__ gsum) {
  __shared__ float aggS[NPB * 16];   // 16 KB: agg row per node
  __shared__ float w2s[1024];        // 4 KB
  __shared__ float b2s[64];
  __shared__ float gacc[GSPAN * 64]; // 2 KB per-graph partial sums
  w2s[threadIdx.x] = W2[threadIdx.x];
  if (threadIdx.x < 64) b2s[threadIdx.x] = b2[threadIdx.x];
  if (threadIdx.x < GSPAN * 64) gacc[threadIdx.x] = 0.f;

  int b = blockIdx.x;
  // ---- phase A: per-node aggregation into LDS (4 lanes/node, reg accumulate) --
  int dl = threadIdx.x >> 2;
  int q = threadIdx.x & 3;
  int node = b * NPB + dl;
  int s0 = b * BCAP + node_off[node];
  int len = cnt[node];
  float o0 = 0.f, o1 = 0.f, o2 = 0.f, o3 = 0.f;
  #pragma unroll 4
  for (int k = 0; k < len; ++k) {
    int srcn = csrg[s0 + k];                                    // broadcast
    uint2 hv = *(const uint2*)(h1h + (size_t)srcn * 8 + q * 2); // 4 lanes = 32B row
    __half2 p0 = *reinterpret_cast<const __half2*>(&hv.x);
    __half2 p1 = *reinterpret_cast<const __half2*>(&hv.y);
    o0 += __low2float(p0); o1 += __high2float(p0);
    o2 += __low2float(p1); o3 += __high2float(p1);
  }
  float di = dinv[node];
  uint2 sv = *(const uint2*)(h1h + (size_t)node * 8 + q * 2);
  __half2 s0h = *reinterpret_cast<const __half2*>(&sv.x);
  __half2 s1h = *reinterpret_cast<const __half2*>(&sv.y);
  aggS[dl * 16 + 4 * q + 0] = di * (o0 + __low2float(s0h));
  aggS[dl * 16 + 4 * q + 1] = di * (o1 + __high2float(s0h));
  aggS[dl * 16 + 4 * q + 2] = di * (o2 + __low2float(s1h));
  aggS[dl * 16 + 4 * q + 3] = di * (o3 + __high2float(s1h));
  __syncthreads();

  // ---- phase B: h2 = relu(agg@W2+b2), pool by graph (wave-uniform node) -------
  int c = threadIdx.x & 63;
  int slot = threadIdx.x >> 6;  // 16 waves, one node per wave per iter
  int g0 = batch[b * NPB];      // first graph in bucket (non-decreasing)
  float racc = 0.f;
  int curli = -1;
  for (int nloc = slot; nloc < NPB; nloc += 16) {
    int nd = b * NPB + nloc;
    int li = batch[nd] - g0;    // wave-uniform
    if (li != curli) {
      if (curli >= 0) {
        if (curli < GSPAN) atomicAdd(&gacc[curli * 64 + c], racc);
        else atomicAdd(&gsum[(size_t)(g0 + curli) * 64 + c], racc);
      }
      curli = li;
      racc = 0.f;
    }
    float v = b2s[c];
    const float* ar = &aggS[nloc * 16];
    #pragma unroll
    for (int k = 0; k < 16; ++k) v += ar[k] * w2s[k * 64 + c];  // broadcast reads
    racc += fmaxf(v, 0.f);
  }
  if (curli >= 0) {
    if (curli < GSPAN) atomicAdd(&gacc[curli * 64 + c], racc);
    else atomicAdd(&gsum[(size_t)(g0 + curli) * 64 + c], racc);
  }
  __syncthreads();

  // ---- flush LDS partials to global -------------------------------------------
  int span = batch[b * NPB + NPB - 1] - g0 + 1;
  if (span > GSPAN) span = GSPAN;
  for (int li = threadIdx.x >> 6; li < span; li += 16) {
    float v = gacc[li * 64 + c];
    atomicAdd(&gsum[(size_t)(g0 + li) * 64 + c], v);
  }
}

// ---- final: per-graph mean + FC MLP (64->32->2) --------------------------------
__global__ __launch_bounds__(64) void k_fc(const float* __restrict__ gsum,
                                           const int* __restrict__ batch,
                                           const float* __restrict__ fcw1,
                                           const float* __restrict__ fcb1,
                                           const float* __restrict__ fcw2,
                                           const float* __restrict__ fcb2,
                                           float* __restrict__ out) {
  int g = blockIdx.x;
  // boundaries via binary search (uniform across threads)
  int lo = 0, hi = N_NODES;
  while (lo < hi) { int m = (lo + hi) >> 1; if (batch[m] < g) lo = m + 1; else hi = m; }
  int start = lo;
  lo = start; hi = N_NODES;
  while (lo < hi) { int m = (lo + hi) >> 1; if (batch[m] < g + 1) lo = m + 1; else hi = m; }
  float inv = 1.0f / fmaxf((float)(lo - start), 1.0f);

  __shared__ float gmean[64];
  gmean[threadIdx.x] = gsum[(size_t)g * 64 + threadIdx.x] * inv;
  __syncthreads();

  __shared__ float hid[32];
  if (threadIdx.x < 32) {
    float a = fcb1[threadIdx.x];
    #pragma unroll
    for (int k = 0; k < 64; ++k) a += gmean[k] * fcw1[k * 32 + threadIdx.x];
    hid[threadIdx.x] = a;
  }
  __syncthreads();

  if (threadIdx.x < 2) {
    float a = fcb2[threadIdx.x];
    #pragma unroll
    for (int k = 0; k < 32; ++k) a += hid[k] * fcw2[k * 2 + threadIdx.x];
    out[g * 2 + threadIdx.x] = a;
  }
}

extern "C" void kernel_launch(void* const* d_in, const int* in_sizes, int n_in,
                              void* d_out, int out_size, void* d_ws, size_t ws_size,
                              hipStream_t stream) {
  const float* x    = (const float*)d_in[0];
  const int*   ei   = (const int*)d_in[1];
  const int*   batch= (const int*)d_in[2];
  const float* W1   = (const float*)d_in[3];
  const float* b1   = (const float*)d_in[4];
  const float* W2   = (const float*)d_in[5];
  const float* b2   = (const float*)d_in[6];
  const float* fcw1 = (const float*)d_in[7];
  const float* fcb1 = (const float*)d_in[8];
  const float* fcw2 = (const float*)d_in[9];
  const float* fcb2 = (const float*)d_in[10];
  float* out = (float*)d_out;

  char* w = (char*)d_ws;
  size_t off = 0;
  auto alloc = [&](size_t bytes) {
    void* p = w + off;
    off += (bytes + 255) & ~(size_t)255;
    return p;
  };
  int*      bcursor  = (int*)     alloc((size_t)NB * 4);
  unsigned* binned   = (unsigned*)alloc((size_t)NB * BCAP * 4);  // 21 MB
  int*      csrg     = (int*)     alloc((size_t)NB * BCAP * 4);  // 21 MB
  float*    dinv     = (float*)   alloc((size_t)N_NODES * 4);
  float4*   xs4      = (float4*)  alloc((size_t)N_NODES * 16);   // 2 MB
  int*      node_off = (int*)     alloc((size_t)N_NODES * 4);
  int*      cnt      = (int*)     alloc((size_t)N_NODES * 4);
  unsigned* h1h      = (unsigned*)alloc((size_t)N_NODES * 32);   // 4 MB fp16
  float*    gsum     = (float*)   alloc((size_t)NUM_GRAPHS * 64 * 4);

  const int* srcp = ei;
  const int* dstp = ei + N_EDGES;

  hipMemsetAsync(gsum, 0, (size_t)NUM_GRAPHS * 64 * 4, stream);
  k_init<<<1, 512, 0, stream>>>(bcursor);
  k_binfill<<<N_EDGES / 16384, 1024, 0, stream>>>(srcp, dstp, bcursor, binned);
  k_sortB<<<NB, 1024, 0, stream>>>(binned, bcursor, x, dinv, xs4, node_off, cnt, csrg);
  k_agg3h1<<<NB, 1024, 0, stream>>>(csrg, node_off, cnt, (const float*)xs4, xs4, dinv, W1, b1, h1h);
  k_agg16pool<<<NB, 1024, 0, stream>>>(csrg, node_off, cnt, h1h, dinv, batch, W2, b2, gsum);
  k_fc<<<NUM_GRAPHS, 64, 0, stream>>>(gsum, batch, fcw1, fcb1, fcw2, fcb2, out);
}